// Round 5
// baseline (68.558 us; speedup 1.0000x reference)
//
#include <hip/hip_runtime.h>
#include <hip/hip_cooperative_groups.h>
#include <math.h>

namespace cg = cooperative_groups;

namespace {
constexpr int S  = 52;
constexpr int SS = S * S;          // 2704
constexpr int A  = 5;
constexpr int NC = 20;
constexpr int CH = 5 + NC;         // 25
constexpr int B  = 32;
constexpr int M  = 50;
constexpr int TSTRIDE = 6;         // xy(2)+wh(2)+conf(1)+cls(1)
constexpr float IGNORE_T = 0.75f;

constexpr int POS_PER_T = 4;
constexpr int CHUNK = 256 * POS_PER_T;                 // 1024 positions per block
constexpr int NBY = (SS + CHUNK - 1) / CHUNK;          // 3
constexpr int NBA = B * A;                             // 160
constexpr int NBLK_NOOBJ = NBA * NBY;                  // 480
constexpr int NBLK = NBLK_NOOBJ + B;                   // 512 total blocks

__device__ __forceinline__ float sigm(float x) { return 1.0f / (1.0f + __expf(-x)); }

__device__ __forceinline__ float iou_one(float px, float py, float pw, float ph,
                                         float gx, float gy, float gw, float gh) {
  float tlx = fmaxf(px - pw * 0.5f, gx - gw * 0.5f);
  float brx = fminf(px + pw * 0.5f, gx + gw * 0.5f);
  float tly = fmaxf(py - ph * 0.5f, gy - gh * 0.5f);
  float bry = fminf(py + ph * 0.5f, gy + gh * 0.5f);
  if (tlx < brx && tly < bry) {
    float ai = (brx - tlx) * (bry - tly);
    return ai / (pw * ph + gw * gh - ai);
  }
  return 0.0f;
}

// Single cooperative kernel, single graph node, no memset:
// each block plain-stores its pre-scaled partial to ws[bid] (full overwrite,
// no init needed), grid.sync(), block 0 reduces 512 floats in fixed order.
__global__ __launch_bounds__(256) void k_fused(const float* __restrict__ outp,
                                               const float* __restrict__ targ,
                                               const float* __restrict__ anch,
                                               float* __restrict__ ws,
                                               float* __restrict__ out) {
  __shared__ float4 sgc[M];
  __shared__ float  sga[M];
  __shared__ float  sg[M][4];
  __shared__ int    sv[M];
  __shared__ int    skey[64];
  __shared__ float  wsum[4];

  const int bid = blockIdx.x;
  const int tid = threadIdx.x;

  if (bid < NBLK_NOOBJ) {
    // ---------------- dense noobj iou-loss ----------------
    // Division-free ignore test: iou>=0.75 <=> 1.75*ai >= 0.75*(pa+ga)
    const int ba = bid % NBA;            // b*A + a
    const int by = bid / NBA;            // chunk index
    const int b  = ba / A, a = ba % A;
    if (tid < M) {
      const float* t = targ + (size_t)(b * M + tid) * TSTRIDE;
      float t0 = t[0], t1 = t[1], t2 = t[2], t3 = t[3], t4 = t[4], t5 = t[5];
      bool valid = (t0 + t1 + t2 + t3 + t4 + t5) > 0.0f;
      float gx = t0 * S, gy = t1 * S, gw = t2 * S, gh = t3 * S;
      float4 c;
      float ga;
      if (valid) {
        c = make_float4(gx - gw * 0.5f, gy - gh * 0.5f, gx + gw * 0.5f, gy + gh * 0.5f);
        ga = 0.75f * gw * gh;
      } else {
        c = make_float4(1e30f, 1e30f, -1e30f, -1e30f);   // never hits
        ga = 0.0f;
      }
      sgc[tid] = c;
      sga[tid] = ga;
    }
    __syncthreads();

    const float aw = anch[2 * a], ah = anch[2 * a + 1];
    const float* base = outp + (size_t)ba * CH * SS;
    const int pos0 = by * CHUNK + tid;

    float ptlx[POS_PER_T], ptly[POS_PER_T], pbrx[POS_PER_T], pbry[POS_PER_T];
    float rhsb[POS_PER_T], pcsq[POS_PER_T];
#pragma unroll
    for (int k = 0; k < POS_PER_T; ++k) {
      int pos = pos0 + k * 256;
      bool act = pos < SS;
      int p = act ? pos : 0;
      float tx = base[p];
      float ty = base[p + SS];
      float tw = base[p + 2 * SS];
      float th = base[p + 3 * SS];
      float tc = base[p + 4 * SS];
      int y = p / S, x = p - y * S;
      float px = sigm(tx) + (float)x;
      float py = sigm(ty) + (float)y;
      float pw = __expf(tw) * aw;
      float ph = __expf(th) * ah;
      ptlx[k] = px - pw * 0.5f;
      ptly[k] = py - ph * 0.5f;
      pbrx[k] = px + pw * 0.5f;
      pbry[k] = py + ph * 0.5f;
      rhsb[k] = 0.75f * (pw * ph);
      float pc = sigm(tc);
      pcsq[k] = act ? pc * pc : 0.0f;
    }

    int covered = 0;
    for (int m = 0; m < M; ++m) {
      float4 g = sgc[m];
      float ga = sga[m];
#pragma unroll
      for (int k = 0; k < POS_PER_T; ++k) {
        float tlx = fmaxf(ptlx[k], g.x);
        float tly = fmaxf(ptly[k], g.y);
        float brx = fminf(pbrx[k], g.z);
        float bry = fminf(pbry[k], g.w);
        float dx = brx - tlx;
        float dy = bry - tly;
        float ai = dx * dy;
        bool hit = (dx > 0.0f) & (dy > 0.0f) & (1.75f * ai >= rhsb[k] + ga);
        covered |= (hit ? 1 : 0) << k;
      }
    }

    float term = 0.0f;
#pragma unroll
    for (int k = 0; k < POS_PER_T; ++k)
      term += (covered >> k & 1) ? 0.0f : pcsq[k];

    for (int off = 32; off > 0; off >>= 1) term += __shfl_down(term, off);
    int lane = tid & 63, wid = tid >> 6;
    if (lane == 0) wsum[wid] = term;
    __syncthreads();
    if (tid == 0)
      ws[bid] = (wsum[0] + wsum[1] + wsum[2] + wsum[3]) * (1.0f / 64.0f);
  } else {
    // ---------------- per-GT sparse corrections ----------------
    const int b = bid - NBLK_NOOBJ;
    const int m = tid;
    int valid = 0;
    float gx = 0, gy = 0, gw = 0, gh = 0;
    int gcls = 0, cx = 0, cy = 0, best = 0;
    float dxv = 0, dyv = 0, dwv = 0, dhv = 0;
    if (m < M) {
      const float* t = targ + (size_t)(b * M + m) * TSTRIDE;
      float t0 = t[0], t1 = t[1], t2 = t[2], t3 = t[3], t4 = t[4], t5 = t[5];
      valid = (t0 + t1 + t2 + t3 + t4 + t5) > 0.0f ? 1 : 0;
      gx = t0 * S; gy = t1 * S; gw = t2 * S; gh = t3 * S;
      gcls = (int)t5;
      sg[m][0] = gx; sg[m][1] = gy; sg[m][2] = gw; sg[m][3] = gh;
      sv[m] = valid;
    }
    if (valid) {
      cx = (int)fminf(fmaxf(floorf(gx - gw * 0.5f), 0.0f), (float)(S - 1));
      cy = (int)fminf(fmaxf(floorf(gy - gh * 0.5f), 0.0f), (float)(S - 1));
      float acx = cx + 0.5f, acy = cy + 0.5f;
      float bestv = -1.0f;
      for (int k = 0; k < A; ++k) {
        float aw = anch[2 * k], ah = anch[2 * k + 1];
        float tlx = fmaxf(acx - aw * 0.5f, gx - gw * 0.5f);
        float brx = fminf(acx + aw * 0.5f, gx + gw * 0.5f);
        float tly = fmaxf(acy - ah * 0.5f, gy - gh * 0.5f);
        float bry = fminf(acy + ah * 0.5f, gy + gh * 0.5f);
        float v = 0.0f;
        if (tlx < brx && tly < bry) {
          float ai = (brx - tlx) * (bry - tly);
          v = ai / (aw * ah + gw * gh - ai);
        }
        if (v > bestv) { bestv = v; best = k; }   // strict > == argmax first-max
      }
      dxv = gx - acx; dyv = gy - acy;
      dwv = gw / anch[2 * best]; dhv = gh / anch[2 * best + 1];
    }
    if (m < 64) skey[m] = valid ? ((cy * S + cx) * A + best) : -1;
    __syncthreads();
    // last-write-wins: winner iff no later valid gt hits same (cell, anchor)
    bool winner = (valid != 0);
    if (winner) {
      int key = skey[m];
      for (int mm = m + 1; mm < M; ++mm)
        if (skey[mm] == key) { winner = false; break; }
    }
    float ciou = 0.0f, cbox = 0.0f, ccls = 0.0f;
    if (winner) {
      int cell = cy * S + cx;
      const float* base = outp + (size_t)(b * A + best) * CH * SS + cell;
      float tx = base[0], ty = base[SS], tw = base[2 * SS], th = base[3 * SS], tc = base[4 * SS];
      float aw = anch[2 * best], ah = anch[2 * best + 1];
      float px = sigm(tx) + (float)cx;
      float py = sigm(ty) + (float)cy;
      float pw = __expf(tw) * aw;
      float ph = __expf(th) * ah;
      float miou = 0.0f;   // recompute max_iou at this single position
      for (int mm = 0; mm < M; ++mm)
        if (sv[mm])
          miou = fmaxf(miou, iou_one(px, py, pw, ph,
                                     sg[mm][0], sg[mm][1], sg[mm][2], sg[mm][3]));
      float pc = sigm(tc);
      float defterm = (miou >= IGNORE_T) ? 0.0f : pc * pc;
      float d5 = 5.0f * (pc - miou);                 // OBJ_SCALE = 5
      ciou = d5 * d5 - defterm;                      // replace default with obj term
      float e0 = sigm(tx) - dxv;
      float e1 = sigm(ty) - dyv;
      float e2 = __expf(tw) - dwv;
      float e3 = __expf(th) - dhv;
      cbox = e0 * e0 + e1 * e1 + e2 * e2 + e3 * e3;
      float l[NC];
      float lmax = -1e30f;
      for (int c = 0; c < NC; ++c) { l[c] = base[(5 + c) * SS]; lmax = fmaxf(lmax, l[c]); }
      float se = 0.0f;
      for (int c = 0; c < NC; ++c) se += __expf(l[c] - lmax);
      ccls = (lmax + __logf(se)) - l[gcls];          // NLL
    }
    if (m < 64) {       // all gt values live in wave 0 (M=50 < 64)
      for (int off = 32; off > 0; off >>= 1) {
        ciou += __shfl_down(ciou, off);
        cbox += __shfl_down(cbox, off);
        ccls += __shfl_down(ccls, off);
      }
      // box: COORD/(2B) = 1/64 ; iou: 1/(2B) = 1/64 ; class: CLASS/B = 1/32
      if (m == 0)
        ws[bid] = (ciou + cbox) * (1.0f / 64.0f) + ccls * (1.0f / 32.0f);
    }
  }

  // ---------------- grid-wide barrier, then block 0 reduces ----------------
  cg::this_grid().sync();
  if (bid == 0) {
    float s = ws[tid] + ws[tid + 256];       // NBLK = 512 partials, fixed order
    for (int off = 32; off > 0; off >>= 1) s += __shfl_down(s, off);
    int lane = tid & 63, wid = tid >> 6;
    if (lane == 0) wsum[wid] = s;
    __syncthreads();
    if (tid == 0)
      out[0] = wsum[0] + wsum[1] + wsum[2] + wsum[3];
  }
}

}  // namespace

extern "C" void kernel_launch(void* const* d_in, const int* in_sizes, int n_in,
                              void* d_out, int out_size, void* d_ws, size_t ws_size,
                              hipStream_t stream) {
  const float* outp = (const float*)d_in[0];
  const float* targ = (const float*)d_in[1];
  const float* anch = (const float*)d_in[2];
  float* ws  = (float*)d_ws;
  float* out = (float*)d_out;

  void* args[] = {(void*)&outp, (void*)&targ, (void*)&anch, (void*)&ws, (void*)&out};
  hipLaunchCooperativeKernel((const void*)k_fused, dim3(NBLK), dim3(256),
                             args, 0, stream);
}

// Round 6
// 31.378 us; speedup vs baseline: 2.1849x; 2.1849x over previous
//
#include <hip/hip_runtime.h>
#include <math.h>

namespace {
constexpr int S  = 52;
constexpr int SS = S * S;          // 2704 (divisible by 4; 52 % 4 == 0)
constexpr int A  = 5;
constexpr int NC = 20;
constexpr int CH = 5 + NC;         // 25
constexpr int B  = 32;
constexpr int M  = 50;
constexpr int TSTRIDE = 6;         // xy(2)+wh(2)+conf(1)+cls(1)
constexpr float IGNORE_T = 0.75f;
constexpr float C37 = 3.0f / 7.0f; // iou>=0.75 <=> ai >= (3/7)*(pa+ga)

constexpr int POS_PER_T = 4;       // 4 CONSECUTIVE positions -> float4 loads
constexpr int CHUNK = 256 * POS_PER_T;                 // 1024 positions per block
constexpr int NBY = (SS + CHUNK - 1) / CHUNK;          // 3
constexpr int NBA = B * A;                             // 160
constexpr int NBLK_NOOBJ = NBA * NBY;                  // 480
constexpr int NBLK = NBLK_NOOBJ + B;                   // 512 total blocks
constexpr int Q4 = SS / 4;                             // 676 float4s per plane

__device__ __forceinline__ float sigm(float x) { return 1.0f / (1.0f + __expf(-x)); }

__device__ __forceinline__ float iou_one(float px, float py, float pw, float ph,
                                         float gx, float gy, float gw, float gh) {
  float tlx = fmaxf(px - pw * 0.5f, gx - gw * 0.5f);
  float brx = fminf(px + pw * 0.5f, gx + gw * 0.5f);
  float tly = fmaxf(py - ph * 0.5f, gy - gh * 0.5f);
  float bry = fminf(py + ph * 0.5f, gy + gh * 0.5f);
  if (tlx < brx && tly < bry) {
    float ai = (brx - tlx) * (bry - tly);
    return ai / (pw * ph + gw * gh - ai);
  }
  return 0.0f;
}

// Single kernel, every block atomically adds its pre-scaled partial into
// out[0] (zeroed by the 4-byte memset node each replay).
__global__ __launch_bounds__(256) void k_fused(const float* __restrict__ outp,
                                               const float* __restrict__ targ,
                                               const float* __restrict__ anch,
                                               float* __restrict__ out) {
  __shared__ float4 sgc[M];   // gt corners tlx,tly,brx,bry
  __shared__ float  sga[M];   // (3/7) * gt area
  __shared__ float  sg[M][4];
  __shared__ int    sv[M];
  __shared__ int    skey[64];
  __shared__ float  wsum[4];

  const int bid = blockIdx.x;
  const int tid = threadIdx.x;

  if (bid < NBLK_NOOBJ) {
    // ---------------- dense noobj iou-loss ----------------
    const int ba = bid % NBA;            // b*A + a
    const int by = bid / NBA;            // chunk index
    const int b  = ba / A, a = ba % A;
    if (tid < M) {
      const float* t = targ + (size_t)(b * M + tid) * TSTRIDE;
      float t0 = t[0], t1 = t[1], t2 = t[2], t3 = t[3], t4 = t[4], t5 = t[5];
      bool valid = (t0 + t1 + t2 + t3 + t4 + t5) > 0.0f;
      float gx = t0 * S, gy = t1 * S, gw = t2 * S, gh = t3 * S;
      if (valid) {
        sgc[tid] = make_float4(gx - gw * 0.5f, gy - gh * 0.5f,
                               gx + gw * 0.5f, gy + gh * 0.5f);
        sga[tid] = C37 * gw * gh;
      } else {
        sgc[tid] = make_float4(1e30f, 1e30f, -1e30f, -1e30f);   // never hits
        sga[tid] = 0.0f;
      }
    }
    __syncthreads();

    const float aw = anch[2 * a], ah = anch[2 * a + 1];
    // float4 index within a plane; clamp inactive threads (last chunk) to a
    // safe in-plane index and zero their contribution.
    int q = by * (CHUNK / 4) + tid;
    const bool act = q < Q4;
    if (!act) q = Q4 - 1;
    const float4* p0 = (const float4*)(outp + (size_t)ba * CH * SS);
    float4 tx4 = p0[q];
    float4 ty4 = p0[q + Q4];
    float4 tw4 = p0[q + 2 * Q4];
    float4 th4 = p0[q + 3 * Q4];
    float4 tc4 = p0[q + 4 * Q4];

    const int pos0 = q * 4;                // 4*q .. 4*q+3 share one row
    const int y = pos0 / S, x0 = pos0 - y * S;
    const float fy = (float)y;

    float ptlx[POS_PER_T], ptly[POS_PER_T], pbrx[POS_PER_T], pbry[POS_PER_T];
    float rhsb[POS_PER_T], pcsq[POS_PER_T];
    const float txx[4] = {tx4.x, tx4.y, tx4.z, tx4.w};
    const float tyy[4] = {ty4.x, ty4.y, ty4.z, ty4.w};
    const float tww[4] = {tw4.x, tw4.y, tw4.z, tw4.w};
    const float thh[4] = {th4.x, th4.y, th4.z, th4.w};
    const float tcc[4] = {tc4.x, tc4.y, tc4.z, tc4.w};
#pragma unroll
    for (int k = 0; k < POS_PER_T; ++k) {
      float px = sigm(txx[k]) + (float)(x0 + k);
      float py = sigm(tyy[k]) + fy;
      float pw = __expf(tww[k]) * aw;
      float ph = __expf(thh[k]) * ah;
      float hw = pw * 0.5f, hh = ph * 0.5f;
      ptlx[k] = px - hw;
      ptly[k] = py - hh;
      pbrx[k] = px + hw;
      pbry[k] = py + hh;
      rhsb[k] = C37 * (pw * ph);
      float pc = sigm(tcc[k]);
      pcsq[k] = act ? pc * pc : 0.0f;
    }

    for (int m = 0; m < M; ++m) {
      float4 g = sgc[m];
      float ga = sga[m];
#pragma unroll
      for (int k = 0; k < POS_PER_T; ++k) {
        float dx = fminf(pbrx[k], g.z) - fmaxf(ptlx[k], g.x);
        float dy = fminf(pbry[k], g.w) - fmaxf(ptly[k], g.y);
        float ai = dx * dy;
        bool hit = (fminf(dx, dy) > 0.0f) & (ai >= rhsb[k] + ga);
        pcsq[k] = hit ? 0.0f : pcsq[k];
      }
    }

    float term = (pcsq[0] + pcsq[1]) + (pcsq[2] + pcsq[3]);
    for (int off = 32; off > 0; off >>= 1) term += __shfl_down(term, off);
    int lane = tid & 63, wid = tid >> 6;
    if (lane == 0) wsum[wid] = term;
    __syncthreads();
    if (tid == 0)
      atomicAdd(out, (wsum[0] + wsum[1] + wsum[2] + wsum[3]) * (1.0f / 64.0f));
  } else {
    // ---------------- per-GT sparse corrections ----------------
    const int b = bid - NBLK_NOOBJ;
    const int m = tid;
    int valid = 0;
    float gx = 0, gy = 0, gw = 0, gh = 0;
    int gcls = 0, cx = 0, cy = 0, best = 0;
    float dxv = 0, dyv = 0, dwv = 0, dhv = 0;
    if (m < M) {
      const float* t = targ + (size_t)(b * M + m) * TSTRIDE;
      float t0 = t[0], t1 = t[1], t2 = t[2], t3 = t[3], t4 = t[4], t5 = t[5];
      valid = (t0 + t1 + t2 + t3 + t4 + t5) > 0.0f ? 1 : 0;
      gx = t0 * S; gy = t1 * S; gw = t2 * S; gh = t3 * S;
      gcls = (int)t5;
      sg[m][0] = gx; sg[m][1] = gy; sg[m][2] = gw; sg[m][3] = gh;
      sv[m] = valid;
    }
    if (valid) {
      cx = (int)fminf(fmaxf(floorf(gx - gw * 0.5f), 0.0f), (float)(S - 1));
      cy = (int)fminf(fmaxf(floorf(gy - gh * 0.5f), 0.0f), (float)(S - 1));
      float acx = cx + 0.5f, acy = cy + 0.5f;
      float bestv = -1.0f;
      for (int k = 0; k < A; ++k) {
        float aw = anch[2 * k], ah = anch[2 * k + 1];
        float tlx = fmaxf(acx - aw * 0.5f, gx - gw * 0.5f);
        float brx = fminf(acx + aw * 0.5f, gx + gw * 0.5f);
        float tly = fmaxf(acy - ah * 0.5f, gy - gh * 0.5f);
        float bry = fminf(acy + ah * 0.5f, gy + gh * 0.5f);
        float v = 0.0f;
        if (tlx < brx && tly < bry) {
          float ai = (brx - tlx) * (bry - tly);
          v = ai / (aw * ah + gw * gh - ai);
        }
        if (v > bestv) { bestv = v; best = k; }   // strict > == argmax first-max
      }
      dxv = gx - acx; dyv = gy - acy;
      dwv = gw / anch[2 * best]; dhv = gh / anch[2 * best + 1];
    }
    if (m < 64) skey[m] = valid ? ((cy * S + cx) * A + best) : -1;
    __syncthreads();
    // last-write-wins: winner iff no later valid gt hits same (cell, anchor)
    bool winner = (valid != 0);
    if (winner) {
      int key = skey[m];
      for (int mm = m + 1; mm < M; ++mm)
        if (skey[mm] == key) { winner = false; break; }
    }
    float ciou = 0.0f, cbox = 0.0f, ccls = 0.0f;
    if (winner) {
      int cell = cy * S + cx;
      const float* base = outp + (size_t)(b * A + best) * CH * SS + cell;
      float tx = base[0], ty = base[SS], tw = base[2 * SS], th = base[3 * SS], tc = base[4 * SS];
      float aw = anch[2 * best], ah = anch[2 * best + 1];
      float px = sigm(tx) + (float)cx;
      float py = sigm(ty) + (float)cy;
      float pw = __expf(tw) * aw;
      float ph = __expf(th) * ah;
      float miou = 0.0f;   // recompute max_iou at this single position
      for (int mm = 0; mm < M; ++mm)
        if (sv[mm])
          miou = fmaxf(miou, iou_one(px, py, pw, ph,
                                     sg[mm][0], sg[mm][1], sg[mm][2], sg[mm][3]));
      float pc = sigm(tc);
      float defterm = (miou >= IGNORE_T) ? 0.0f : pc * pc;
      float d5 = 5.0f * (pc - miou);                 // OBJ_SCALE = 5
      ciou = d5 * d5 - defterm;                      // replace default with obj term
      float e0 = sigm(tx) - dxv;
      float e1 = sigm(ty) - dyv;
      float e2 = __expf(tw) - dwv;
      float e3 = __expf(th) - dhv;
      cbox = e0 * e0 + e1 * e1 + e2 * e2 + e3 * e3;
      float l[NC];
      float lmax = -1e30f;
      for (int c = 0; c < NC; ++c) { l[c] = base[(5 + c) * SS]; lmax = fmaxf(lmax, l[c]); }
      float se = 0.0f;
      for (int c = 0; c < NC; ++c) se += __expf(l[c] - lmax);
      ccls = (lmax + __logf(se)) - l[gcls];          // NLL
    }
    if (m < 64) {       // all gt values live in wave 0 (M=50 < 64)
      for (int off = 32; off > 0; off >>= 1) {
        ciou += __shfl_down(ciou, off);
        cbox += __shfl_down(cbox, off);
        ccls += __shfl_down(ccls, off);
      }
      // box: COORD/(2B) = 1/64 ; iou: 1/(2B) = 1/64 ; class: CLASS/B = 1/32
      if (m == 0)
        atomicAdd(out, (ciou + cbox) * (1.0f / 64.0f) + ccls * (1.0f / 32.0f));
    }
  }
}

}  // namespace

extern "C" void kernel_launch(void* const* d_in, const int* in_sizes, int n_in,
                              void* d_out, int out_size, void* d_ws, size_t ws_size,
                              hipStream_t stream) {
  const float* outp = (const float*)d_in[0];
  const float* targ = (const float*)d_in[1];
  const float* anch = (const float*)d_in[2];

  hipMemsetAsync(d_out, 0, 4, stream);   // zero the scalar accumulator each replay
  k_fused<<<NBLK, 256, 0, stream>>>(outp, targ, anch, (float*)d_out);
}

// Round 7
// 29.263 us; speedup vs baseline: 2.3429x; 1.0723x over previous
//
#include <hip/hip_runtime.h>
#include <math.h>

namespace {
constexpr int S  = 52;
constexpr int SS = S * S;          // 2704 (divisible by 4; 52 % 4 == 0)
constexpr int A  = 5;
constexpr int NC = 20;
constexpr int CH = 5 + NC;         // 25
constexpr int B  = 32;
constexpr int M  = 50;
constexpr int TSTRIDE = 6;         // xy(2)+wh(2)+conf(1)+cls(1)
constexpr float IGNORE_T = 0.75f;
constexpr float C37 = 3.0f / 7.0f; // iou>=0.75 <=> ai >= (3/7)*(pa+ga)

constexpr int POS_PER_T = 4;       // 4 consecutive positions -> float4 loads
constexpr int CHUNK = 256 * POS_PER_T;                 // 1024 positions per block
constexpr int NBY = (SS + CHUNK - 1) / CHUNK;          // 3
constexpr int NBA = B * A;                             // 160
constexpr int NBLK_NOOBJ = NBA * NBY;                  // 480
constexpr int NPROD = NBLK_NOOBJ + B;                  // 512 producer blocks
constexpr int NBLK = NPROD + 1;                        // +1 reducer (bid 0)
constexpr int Q4 = SS / 4;                             // 676 float4s per plane
constexpr unsigned MAGIC = 0x5F3759DFu;

__device__ __forceinline__ float sigm(float x) { return 1.0f / (1.0f + __expf(-x)); }

__device__ __forceinline__ float iou_one(float px, float py, float pw, float ph,
                                         float gx, float gy, float gw, float gh) {
  float tlx = fmaxf(px - pw * 0.5f, gx - gw * 0.5f);
  float brx = fminf(px + pw * 0.5f, gx + gw * 0.5f);
  float tly = fmaxf(py - ph * 0.5f, gy - gh * 0.5f);
  float bry = fminf(py + ph * 0.5f, gy + gh * 0.5f);
  if (tlx < brx && tly < bry) {
    float ai = (brx - tlx) * (bry - tly);
    return ai / (pw * ph + gw * gh - ai);
  }
  return 0.0f;
}

__device__ __forceinline__ void publish(float* partials, unsigned* flags, int p,
                                        float v) {
  partials[p] = v;
  __threadfence();   // make partial visible device-wide before the flag
  __hip_atomic_store(&flags[p], MAGIC, __ATOMIC_RELEASE, __HIP_MEMORY_SCOPE_AGENT);
}

// ONE kernel, ONE graph node, no memset. Block 0 = reducer (spins on flags,
// fixed-order sum, plain store to out, resets flags -> self-cleaning across
// graph replays). Blocks 1..NPROD = producers.
__global__ __launch_bounds__(256) void k_fused(const float* __restrict__ outp,
                                               const float* __restrict__ targ,
                                               const float* __restrict__ anch,
                                               float* __restrict__ partials,
                                               unsigned* __restrict__ flags,
                                               float* __restrict__ out) {
  __shared__ float4 sgc[M];
  __shared__ float  sga[M];
  __shared__ float  sg[M][4];
  __shared__ int    sv[M];
  __shared__ int    skey[64];
  __shared__ float  wsum[4];

  const int bid = blockIdx.x;
  const int tid = threadIdx.x;

  if (bid == 0) {
    // ---------------- reducer: wait for all 512 partials ----------------
    const int i0 = tid, i1 = tid + 256;
    while (__hip_atomic_load(&flags[i0], __ATOMIC_ACQUIRE,
                             __HIP_MEMORY_SCOPE_AGENT) != MAGIC)
      __builtin_amdgcn_s_sleep(2);
    while (__hip_atomic_load(&flags[i1], __ATOMIC_ACQUIRE,
                             __HIP_MEMORY_SCOPE_AGENT) != MAGIC)
      __builtin_amdgcn_s_sleep(2);
    float s = __hip_atomic_load(&partials[i0], __ATOMIC_RELAXED,
                                __HIP_MEMORY_SCOPE_AGENT) +
              __hip_atomic_load(&partials[i1], __ATOMIC_RELAXED,
                                __HIP_MEMORY_SCOPE_AGENT);
    for (int off = 32; off > 0; off >>= 1) s += __shfl_down(s, off);
    int lane = tid & 63, wid = tid >> 6;
    if (lane == 0) wsum[wid] = s;
    __syncthreads();
    if (tid == 0)
      out[0] = wsum[0] + wsum[1] + wsum[2] + wsum[3];   // plain store, no init needed
    // self-clean for the next replay
    __hip_atomic_store(&flags[i0], 0u, __ATOMIC_RELAXED, __HIP_MEMORY_SCOPE_AGENT);
    __hip_atomic_store(&flags[i1], 0u, __ATOMIC_RELAXED, __HIP_MEMORY_SCOPE_AGENT);
    return;
  }

  const int p = bid - 1;   // producer index, 0..NPROD-1

  if (p < NBLK_NOOBJ) {
    // ---------------- dense noobj iou-loss ----------------
    const int ba = p % NBA;              // b*A + a
    const int by = p / NBA;              // chunk index
    const int b  = ba / A, a = ba % A;
    if (tid < M) {
      const float* t = targ + (size_t)(b * M + tid) * TSTRIDE;
      float t0 = t[0], t1 = t[1], t2 = t[2], t3 = t[3], t4 = t[4], t5 = t[5];
      bool valid = (t0 + t1 + t2 + t3 + t4 + t5) > 0.0f;
      float gx = t0 * S, gy = t1 * S, gw = t2 * S, gh = t3 * S;
      if (valid) {
        sgc[tid] = make_float4(gx - gw * 0.5f, gy - gh * 0.5f,
                               gx + gw * 0.5f, gy + gh * 0.5f);
        sga[tid] = C37 * gw * gh;
      } else {
        sgc[tid] = make_float4(1e30f, 1e30f, -1e30f, -1e30f);   // never hits
        sga[tid] = 0.0f;
      }
    }
    __syncthreads();

    const float aw = anch[2 * a], ah = anch[2 * a + 1];
    int q = by * (CHUNK / 4) + tid;
    const bool act = q < Q4;
    if (!act) q = Q4 - 1;
    const float4* p0 = (const float4*)(outp + (size_t)ba * CH * SS);
    float4 tx4 = p0[q];
    float4 ty4 = p0[q + Q4];
    float4 tw4 = p0[q + 2 * Q4];
    float4 th4 = p0[q + 3 * Q4];
    float4 tc4 = p0[q + 4 * Q4];

    const int pos0 = q * 4;              // 4*q .. 4*q+3 share one row
    const int y = pos0 / S, x0 = pos0 - y * S;
    const float fy = (float)y;

    float ptlx[POS_PER_T], ptly[POS_PER_T], pbrx[POS_PER_T], pbry[POS_PER_T];
    float rhsb[POS_PER_T], pcsq[POS_PER_T];
    const float txx[4] = {tx4.x, tx4.y, tx4.z, tx4.w};
    const float tyy[4] = {ty4.x, ty4.y, ty4.z, ty4.w};
    const float tww[4] = {tw4.x, tw4.y, tw4.z, tw4.w};
    const float thh[4] = {th4.x, th4.y, th4.z, th4.w};
    const float tcc[4] = {tc4.x, tc4.y, tc4.z, tc4.w};
#pragma unroll
    for (int k = 0; k < POS_PER_T; ++k) {
      float px = sigm(txx[k]) + (float)(x0 + k);
      float py = sigm(tyy[k]) + fy;
      float pw = __expf(tww[k]) * aw;
      float ph = __expf(thh[k]) * ah;
      float hw = pw * 0.5f, hh = ph * 0.5f;
      ptlx[k] = px - hw;
      ptly[k] = py - hh;
      pbrx[k] = px + hw;
      pbry[k] = py + hh;
      rhsb[k] = C37 * (pw * ph);
      float pc = sigm(tcc[k]);
      pcsq[k] = act ? pc * pc : 0.0f;
    }

    for (int m = 0; m < M; ++m) {
      float4 g = sgc[m];
      float ga = sga[m];
#pragma unroll
      for (int k = 0; k < POS_PER_T; ++k) {
        float dx = fminf(pbrx[k], g.z) - fmaxf(ptlx[k], g.x);
        float dy = fminf(pbry[k], g.w) - fmaxf(ptly[k], g.y);
        float ai = dx * dy;
        bool hit = (fminf(dx, dy) > 0.0f) & (ai >= rhsb[k] + ga);
        pcsq[k] = hit ? 0.0f : pcsq[k];
      }
    }

    float term = (pcsq[0] + pcsq[1]) + (pcsq[2] + pcsq[3]);
    for (int off = 32; off > 0; off >>= 1) term += __shfl_down(term, off);
    int lane = tid & 63, wid = tid >> 6;
    if (lane == 0) wsum[wid] = term;
    __syncthreads();
    if (tid == 0)
      publish(partials, flags, p,
              (wsum[0] + wsum[1] + wsum[2] + wsum[3]) * (1.0f / 64.0f));
  } else {
    // ---------------- per-GT sparse corrections ----------------
    const int b = p - NBLK_NOOBJ;
    const int m = tid;
    int valid = 0;
    float gx = 0, gy = 0, gw = 0, gh = 0;
    int gcls = 0, cx = 0, cy = 0, best = 0;
    float dxv = 0, dyv = 0, dwv = 0, dhv = 0;
    if (m < M) {
      const float* t = targ + (size_t)(b * M + m) * TSTRIDE;
      float t0 = t[0], t1 = t[1], t2 = t[2], t3 = t[3], t4 = t[4], t5 = t[5];
      valid = (t0 + t1 + t2 + t3 + t4 + t5) > 0.0f ? 1 : 0;
      gx = t0 * S; gy = t1 * S; gw = t2 * S; gh = t3 * S;
      gcls = (int)t5;
      sg[m][0] = gx; sg[m][1] = gy; sg[m][2] = gw; sg[m][3] = gh;
      sv[m] = valid;
    }
    if (valid) {
      cx = (int)fminf(fmaxf(floorf(gx - gw * 0.5f), 0.0f), (float)(S - 1));
      cy = (int)fminf(fmaxf(floorf(gy - gh * 0.5f), 0.0f), (float)(S - 1));
      float acx = cx + 0.5f, acy = cy + 0.5f;
      float bestv = -1.0f;
      for (int k = 0; k < A; ++k) {
        float aw = anch[2 * k], ah = anch[2 * k + 1];
        float tlx = fmaxf(acx - aw * 0.5f, gx - gw * 0.5f);
        float brx = fminf(acx + aw * 0.5f, gx + gw * 0.5f);
        float tly = fmaxf(acy - ah * 0.5f, gy - gh * 0.5f);
        float bry = fminf(acy + ah * 0.5f, gy + gh * 0.5f);
        float v = 0.0f;
        if (tlx < brx && tly < bry) {
          float ai = (brx - tlx) * (bry - tly);
          v = ai / (aw * ah + gw * gh - ai);
        }
        if (v > bestv) { bestv = v; best = k; }   // strict > == argmax first-max
      }
      dxv = gx - acx; dyv = gy - acy;
      dwv = gw / anch[2 * best]; dhv = gh / anch[2 * best + 1];
    }
    if (m < 64) skey[m] = valid ? ((cy * S + cx) * A + best) : -1;
    __syncthreads();
    // last-write-wins: winner iff no later valid gt hits same (cell, anchor)
    bool winner = (valid != 0);
    if (winner) {
      int key = skey[m];
      for (int mm = m + 1; mm < M; ++mm)
        if (skey[mm] == key) { winner = false; break; }
    }
    float ciou = 0.0f, cbox = 0.0f, ccls = 0.0f;
    if (winner) {
      int cell = cy * S + cx;
      const float* base = outp + (size_t)(b * A + best) * CH * SS + cell;
      float tx = base[0], ty = base[SS], tw = base[2 * SS], th = base[3 * SS], tc = base[4 * SS];
      float aw = anch[2 * best], ah = anch[2 * best + 1];
      float px = sigm(tx) + (float)cx;
      float py = sigm(ty) + (float)cy;
      float pw = __expf(tw) * aw;
      float ph = __expf(th) * ah;
      float miou = 0.0f;   // recompute max_iou at this single position
      for (int mm = 0; mm < M; ++mm)
        if (sv[mm])
          miou = fmaxf(miou, iou_one(px, py, pw, ph,
                                     sg[mm][0], sg[mm][1], sg[mm][2], sg[mm][3]));
      float pc = sigm(tc);
      float defterm = (miou >= IGNORE_T) ? 0.0f : pc * pc;
      float d5 = 5.0f * (pc - miou);                 // OBJ_SCALE = 5
      ciou = d5 * d5 - defterm;                      // replace default with obj term
      float e0 = sigm(tx) - dxv;
      float e1 = sigm(ty) - dyv;
      float e2 = __expf(tw) - dwv;
      float e3 = __expf(th) - dhv;
      cbox = e0 * e0 + e1 * e1 + e2 * e2 + e3 * e3;
      float l[NC];
      float lmax = -1e30f;
      for (int c = 0; c < NC; ++c) { l[c] = base[(5 + c) * SS]; lmax = fmaxf(lmax, l[c]); }
      float se = 0.0f;
      for (int c = 0; c < NC; ++c) se += __expf(l[c] - lmax);
      ccls = (lmax + __logf(se)) - l[gcls];          // NLL
    }
    if (m < 64) {       // all gt values live in wave 0 (M=50 < 64)
      for (int off = 32; off > 0; off >>= 1) {
        ciou += __shfl_down(ciou, off);
        cbox += __shfl_down(cbox, off);
        ccls += __shfl_down(ccls, off);
      }
      // box: COORD/(2B) = 1/64 ; iou: 1/(2B) = 1/64 ; class: CLASS/B = 1/32
      if (m == 0)
        publish(partials, flags, p,
                (ciou + cbox) * (1.0f / 64.0f) + ccls * (1.0f / 32.0f));
    }
  }
}

}  // namespace

extern "C" void kernel_launch(void* const* d_in, const int* in_sizes, int n_in,
                              void* d_out, int out_size, void* d_ws, size_t ws_size,
                              hipStream_t stream) {
  const float* outp = (const float*)d_in[0];
  const float* targ = (const float*)d_in[1];
  const float* anch = (const float*)d_in[2];
  float*    partials = (float*)d_ws;                 // [NPROD]
  unsigned* flags    = (unsigned*)((float*)d_ws + NPROD);  // [NPROD], self-cleaning

  k_fused<<<NBLK, 256, 0, stream>>>(outp, targ, anch, partials, flags,
                                    (float*)d_out);
}